// Round 1
// baseline (62.765 us; speedup 1.0000x reference)
//
#include <hip/hip_runtime.h>
#include <math.h>

// Exact replay of: y = 0; repeat 1e6: y = f32_rne(y + eps)   (sequential f32)
// plus x_double = f32(1e6 * (double)eps), out = |x_double - y|.
//
// Fast-forward trick: within one f32 binade, RNE(y + c) advances the bit
// pattern by a CONSTANT integer stride s (ties-to-even settles after one
// step, and tie cases with unsettled parity fail the equal-stride guard).
// So: take 2 real FP steps, verify 3 consecutive points share a binade with
// equal bit strides, then jump k*s in bit space (k capped to stay strictly
// inside the binade and to the remaining step budget). Binade crossings and
// tie-settling are handled by real FP adds. O(~100) iterations total.
__global__ void eps_accum_kernel(const float* __restrict__ eps_p,
                                 float* __restrict__ out) {
    if (threadIdx.x != 0 || blockIdx.x != 0) return;

    const float c = eps_p[0];
    long long rem = 1000000LL;
    float y = 0.0f;

    while (rem > 0) {
        float y1 = y + c;
        if (y1 == y) { break; }              // fixed point: rest are no-ops
        if (rem == 1) { y = y1; break; }     // last step
        float y2 = y1 + c;
        if (y2 == y1) { y = y1; break; }     // fixed after consuming 1 step

        long long u0 = (long long)__float_as_uint(y);
        long long u1 = (long long)__float_as_uint(y1);
        long long u2 = (long long)__float_as_uint(y2);
        long long s  = u2 - u1;

        // Jump is valid only if y, y1, y2 all sit in the same binade and the
        // two observed strides match (rejects unsettled ties-to-even parity).
        if (s > 0 && (u1 - u0) == s && (u0 >> 23) == (u2 >> 23)) {
            long long top  = (((u2 >> 23) + 1) << 23);   // binade-top pattern
            long long maxk = (top - 1 - u1) / s;         // stay inside binade
            long long k    = maxk < (rem - 1) ? maxk : (rem - 1);
            if (k >= 1) {
                y = __uint_as_float((unsigned int)(u1 + k * s));
                rem -= (1 + k);
                continue;
            }
        }
        // Fallback: consume both real FP steps (guarantees progress).
        y = y2;
        rem -= 2;
    }

    // x-path: reference accumulates the python double 0.001; we only have
    // f32 eps. 1e6 * (double)eps then cast to f32 differs from the reference
    // value (1000.0f) by one f32 ulp at 1000 (6.1e-5) -- far under the
    // 1.775e-1 threshold. Serial double accumulation would change nothing
    // at f32 precision vs the multiply.
    float xd = (float)(1000000.0 * (double)c);
    out[0] = fabsf(xd - y);
}

extern "C" void kernel_launch(void* const* d_in, const int* in_sizes, int n_in,
                              void* d_out, int out_size, void* d_ws, size_t ws_size,
                              hipStream_t stream) {
    // inputs: d_in[0] = x (1024*1024 f32, ignored), d_in[1] = eps (1 f32).
    // Pick the size-1 input defensively.
    int eps_idx = 1;
    for (int i = 0; i < n_in; ++i) {
        if (in_sizes[i] == 1) { eps_idx = i; break; }
    }
    const float* eps = (const float*)d_in[eps_idx];
    float* out = (float*)d_out;
    eps_accum_kernel<<<1, 64, 0, stream>>>(eps, out);
}